// Round 2
// baseline (30339.273 us; speedup 1.0000x reference)
//
#include <hip/hip_runtime.h>
#include <hip/hip_fp16.h>

#define T_LEN 8192
#define E_DIM 512
#define H_DIM 512
#define G4    2048   // 4*H
#define KTAGS 19
#define START_TAG 17
#define STOP_TAG  18
#define NEGV  (-10000.0f)
#define NWG   32     // workgroups per direction

__device__ __forceinline__ float sigmoidf_(float x) { return 1.0f / (1.0f + expf(-x)); }

// ---------------- K1: xg[dir][t][n] = dot(x[t or T-1-t], w_ih[n]) + b_ih[n] + b_hh[n]
template<bool XG16>
__global__ __launch_bounds__(256) void k_xg(
    const float* __restrict__ x,
    const float* __restrict__ wih_f, const float* __restrict__ bih_f, const float* __restrict__ bhh_f,
    const float* __restrict__ wih_b, const float* __restrict__ bih_b, const float* __restrict__ bhh_b,
    void* __restrict__ xg_out)
{
  const int dir = blockIdx.z;
  const float* __restrict__ wih = dir ? wih_b : wih_f;
  const float* __restrict__ bih = dir ? bih_b : bih_f;
  const float* __restrict__ bhh = dir ? bhh_b : bhh_f;
  __shared__ float xs[16][68];   // [k][m] transposed-on-write, padded
  __shared__ float wsd[16][68];  // [k][n]
  const int tid = threadIdx.x;
  const int tm = tid >> 4, tn = tid & 15;
  const int m0 = blockIdx.y * 64, n0 = blockIdx.x * 64;
  const int lr = tid >> 2;          // 0..63: tile row
  const int lk = (tid & 3) << 2;    // 0,4,8,12
  float acc[4][4] = {{0.f,0.f,0.f,0.f},{0.f,0.f,0.f,0.f},{0.f,0.f,0.f,0.f},{0.f,0.f,0.f,0.f}};
  for (int k0 = 0; k0 < E_DIM; k0 += 16) {
    const int gm = m0 + lr;
    const int xrow = dir ? (T_LEN - 1 - gm) : gm;
    const float4 xa = *reinterpret_cast<const float4*>(&x[(size_t)xrow * E_DIM + k0 + lk]);
    const float4 wa = *reinterpret_cast<const float4*>(&wih[(size_t)(n0 + lr) * E_DIM + k0 + lk]);
    __syncthreads();
    xs[lk+0][lr] = xa.x; xs[lk+1][lr] = xa.y; xs[lk+2][lr] = xa.z; xs[lk+3][lr] = xa.w;
    wsd[lk+0][lr] = wa.x; wsd[lk+1][lr] = wa.y; wsd[lk+2][lr] = wa.z; wsd[lk+3][lr] = wa.w;
    __syncthreads();
    #pragma unroll
    for (int kk = 0; kk < 16; ++kk) {
      const float4 a = *reinterpret_cast<const float4*>(&xs[kk][tm << 2]);
      const float4 b = *reinterpret_cast<const float4*>(&wsd[kk][tn << 2]);
      acc[0][0] += a.x*b.x; acc[0][1] += a.x*b.y; acc[0][2] += a.x*b.z; acc[0][3] += a.x*b.w;
      acc[1][0] += a.y*b.x; acc[1][1] += a.y*b.y; acc[1][2] += a.y*b.z; acc[1][3] += a.y*b.w;
      acc[2][0] += a.z*b.x; acc[2][1] += a.z*b.y; acc[2][2] += a.z*b.z; acc[2][3] += a.z*b.w;
      acc[3][0] += a.w*b.x; acc[3][1] += a.w*b.y; acc[3][2] += a.w*b.z; acc[3][3] += a.w*b.w;
    }
  }
  const int n = n0 + (tn << 2);
  float4 bb;
  bb.x = bih[n+0] + bhh[n+0];
  bb.y = bih[n+1] + bhh[n+1];
  bb.z = bih[n+2] + bhh[n+2];
  bb.w = bih[n+3] + bhh[n+3];
  if (XG16) {
    __half* o = reinterpret_cast<__half*>(xg_out) + (size_t)dir * T_LEN * G4;
    #pragma unroll
    for (int mi = 0; mi < 4; ++mi) {
      const size_t base = (size_t)(m0 + (tm << 2) + mi) * G4 + n;
      o[base+0] = __float2half(acc[mi][0] + bb.x);
      o[base+1] = __float2half(acc[mi][1] + bb.y);
      o[base+2] = __float2half(acc[mi][2] + bb.z);
      o[base+3] = __float2half(acc[mi][3] + bb.w);
    }
  } else {
    float* o = reinterpret_cast<float*>(xg_out) + (size_t)dir * T_LEN * G4;
    #pragma unroll
    for (int mi = 0; mi < 4; ++mi) {
      const size_t base = (size_t)(m0 + (tm << 2) + mi) * G4 + n;
      float4 st; st.x = acc[mi][0] + bb.x; st.y = acc[mi][1] + bb.y;
      st.z = acc[mi][2] + bb.z; st.w = acc[mi][3] + bb.w;
      *reinterpret_cast<float4*>(&o[base]) = st;
    }
  }
}

// ---------------- K2: persistent bidirectional LSTM recurrence.
// 64 blocks x 512 threads: dir = b&1, slice idx = b>>1 (32 slices/dir of 16 h each).
// Wave w handles k-chunk [w*64, w*64+64); lane l = local gate row (4 gates x 16 h).
// Per-thread weights: 16 float4 (64 VGPRs) -> compiler keeps them resident.
// Step sync: per-producer flag words (release store t+1), no RMW serialization.
template<bool XG16>
__global__ __launch_bounds__(512, 2) void k_lstm(
    const float* __restrict__ whh_f, const float* __restrict__ whh_b,
    const float* __restrict__ h0, const float* __restrict__ c0,
    const void* __restrict__ xg_base, float* __restrict__ h_hist,
    unsigned int* __restrict__ flags)
{
  const int b = blockIdx.x;
  const int dir = b & 1;
  const int idx = b >> 1;                  // 0..31
  const float* __restrict__ whh = dir ? whh_b : whh_f;
  const float* xg32 = reinterpret_cast<const float*>(xg_base) + (size_t)dir * T_LEN * G4;
  const __half* xg16 = reinterpret_cast<const __half*>(xg_base) + (size_t)dir * T_LEN * G4;
  float* hh = h_hist + (size_t)dir * T_LEN * H_DIM;
  unsigned int* fl = flags + dir * NWG * 32;   // 32 uints (128B) stride per flag

  const int tid = threadIdx.x;
  const int w = tid >> 6;        // 0..7: k-chunk
  const int l = tid & 63;        // 0..63: local gate row
  const int gate = l >> 4, j = l & 15;
  const int H0 = idx * 16;
  const int R = gate * H_DIM + H0 + j;     // global gate row (i,f,g,o blocks)

  // 64 weight floats per thread, static-indexed -> VGPR-resident
  float4 wreg[16];
  {
    const float4* wr4 = reinterpret_cast<const float4*>(&whh[(size_t)R * H_DIM + w * 64]);
    #pragma unroll
    for (int kk = 0; kk < 16; ++kk) wreg[kk] = wr4[kk];
  }

  __shared__ float h_lds[H_DIM];
  __shared__ float pg[8 * 64];
  float cstate = (tid < 16) ? c0[dir * H_DIM + H0 + tid] : 0.f;

  float xcur = 0.f;
  if (w == 0) xcur = XG16 ? __half2float(xg16[R]) : xg32[R];

  for (int t = 0; t < T_LEN; ++t) {
    // prefetch next step's xg row value; hides L2 latency under the flag wait
    float xnext = 0.f;
    if (w == 0 && t + 1 < T_LEN)
      xnext = XG16 ? __half2float(xg16[(size_t)(t + 1) * G4 + R])
                   : xg32[(size_t)(t + 1) * G4 + R];

    float hv;
    if (t > 0) {
      if (tid < NWG) {
        const unsigned int* fp = &fl[tid * 32];
        while (__hip_atomic_load(fp, __ATOMIC_ACQUIRE, __HIP_MEMORY_SCOPE_AGENT) < (unsigned)t)
          __builtin_amdgcn_s_sleep(1);
      }
      __syncthreads();
      hv = __hip_atomic_load(&hh[(size_t)(t - 1) * H_DIM + tid],
                             __ATOMIC_RELAXED, __HIP_MEMORY_SCOPE_AGENT);
    } else {
      hv = h0[dir * H_DIM + tid];
    }
    h_lds[tid] = hv;
    __syncthreads();

    // partial dot: wave w covers k in [w*64, w*64+64) -> LDS reads are wave-broadcast
    float acc = 0.f;
    const float* hc = &h_lds[w * 64];
    #pragma unroll
    for (int kk = 0; kk < 16; ++kk) {
      const float4 h4 = *reinterpret_cast<const float4*>(&hc[kk << 2]);
      const float4 wv = wreg[kk];
      acc += wv.x * h4.x + wv.y * h4.y + wv.z * h4.z + wv.w * h4.w;
    }
    pg[w * 64 + l] = acc;
    __syncthreads();

    if (tid < 64) {
      float g = xcur;
      #pragma unroll
      for (int ww = 0; ww < 8; ++ww) g += pg[ww * 64 + tid];
      // gather the 4 gates of h-index j into lanes 0..15 (full wave0 in shfl)
      const float gi = __shfl(g, j, 64);
      const float gf = __shfl(g, 16 + j, 64);
      const float gg = __shfl(g, 32 + j, 64);
      const float go = __shfl(g, 48 + j, 64);
      if (tid < 16) {
        cstate = sigmoidf_(gf) * cstate + sigmoidf_(gi) * tanhf(gg);
        const float hval = sigmoidf_(go) * tanhf(cstate);
        __hip_atomic_store(&hh[(size_t)t * H_DIM + H0 + tid], hval,
                           __ATOMIC_RELAXED, __HIP_MEMORY_SCOPE_AGENT);
      }
    }
    __syncthreads();   // compiler drains vmcnt before s_barrier: h stores device-visible
    if (tid == 0)
      __hip_atomic_store(&fl[idx * 32], (unsigned)(t + 1),
                         __ATOMIC_RELEASE, __HIP_MEMORY_SCOPE_AGENT);
    xcur = xnext;
  }
}

// ---------------- K3: feats[t][k] = b_tag[k] + [h_f(t), h_b(T-1-t)] . W_tag[k]
__global__ __launch_bounds__(64) void k_feats(
    const float* __restrict__ h_hist, const float* __restrict__ Wtag,
    const float* __restrict__ btag, float* __restrict__ feats)
{
  const int t = blockIdx.x;
  const int k = threadIdx.x;
  if (k >= KTAGS) return;
  const float* hf  = &h_hist[(size_t)t * H_DIM];
  const float* hbp = &h_hist[(size_t)T_LEN * H_DIM + (size_t)(T_LEN - 1 - t) * H_DIM];
  const float* wr  = &Wtag[(size_t)k * (2 * H_DIM)];
  float acc = btag[k];
  #pragma unroll 8
  for (int d = 0; d < H_DIM / 4; ++d) {
    const float4 h4 = *reinterpret_cast<const float4*>(&hf[d << 2]);
    const float4 w4 = *reinterpret_cast<const float4*>(&wr[d << 2]);
    acc += h4.x*w4.x + h4.y*w4.y + h4.z*w4.z + h4.w*w4.w;
  }
  #pragma unroll 8
  for (int d = 0; d < H_DIM / 4; ++d) {
    const float4 h4 = *reinterpret_cast<const float4*>(&hbp[d << 2]);
    const float4 w4 = *reinterpret_cast<const float4*>(&wr[H_DIM + (d << 2)]);
    acc += h4.x*w4.x + h4.y*w4.y + h4.z*w4.z + h4.w*w4.w;
  }
  feats[(size_t)t * KTAGS + k] = acc;
}

// ---------------- K4: Viterbi forward scan (1 wave; fv in regs, shfl broadcast)
// ILP form: 19 independent candidates, 5-level fmax tree, eq-bitmask argmax (first max).
__global__ __launch_bounds__(64) void k_viterbi(
    const float* __restrict__ feats, const float* __restrict__ trans,
    float* __restrict__ d_out, unsigned char* __restrict__ bptr, int* __restrict__ best)
{
  const int l = threadIdx.x;
  const bool act = (l < KTAGS);
  float trow[KTAGS];
  #pragma unroll
  for (int jj = 0; jj < KTAGS; ++jj)
    trow[jj] = act ? trans[l * KTAGS + jj] : NEGV;
  const float trs = act ? trans[STOP_TAG * KTAGS + l] : NEGV;
  float fv = act ? ((l == START_TAG) ? 0.f : NEGV) : -3.4e38f;
  float fbuf[8];
  #pragma unroll
  for (int q = 0; q < 8; ++q) fbuf[q] = act ? feats[(size_t)q * KTAGS + l] : 0.f;

  for (int t = 0; t < T_LEN; t += 8) {
    #pragma unroll
    for (int u = 0; u < 8; ++u) {
      const int tt = t + u;
      const float fcur = fbuf[u];
      if (act && (tt + 8 < T_LEN)) fbuf[u] = feats[(size_t)(tt + 8) * KTAGS + l];
      float v[KTAGS];
      #pragma unroll
      for (int jj = 0; jj < KTAGS; ++jj)
        v[jj] = __shfl(fv, jj, 64) + trow[jj];
      // 5-level max tree over 19
      float a[10];
      #pragma unroll
      for (int q = 0; q < 9; ++q) a[q] = fmaxf(v[2*q], v[2*q+1]);
      a[9] = v[18];
      float bb0 = fmaxf(a[0], a[1]), bb1 = fmaxf(a[2], a[3]);
      float bb2 = fmaxf(a[4], a[5]), bb3 = fmaxf(a[6], a[7]);
      float bb4 = fmaxf(a[8], a[9]);
      const float mv = fmaxf(fmaxf(fmaxf(bb0, bb1), fmaxf(bb2, bb3)), bb4);
      unsigned bits = 0u;
      #pragma unroll
      for (int jj = 0; jj < KTAGS; ++jj)
        bits |= (v[jj] == mv) ? (1u << jj) : 0u;
      const int am = __ffs(bits) - 1;       // first max = smallest j (matches argmax)
      fv = mv + fcur;
      if (act) bptr[(size_t)tt * KTAGS + l] = (unsigned char)am;
    }
  }
  float tv = act ? (fv + trs) : -3.4e38f;
  int bi = l;
  #pragma unroll
  for (int off = 1; off < 64; off <<= 1) {
    const float ov = __shfl_xor(tv, off, 64);
    const int oi = __shfl_xor(bi, off, 64);
    if (ov > tv || (ov == tv && oi < bi)) { tv = ov; bi = oi; }
  }
  if (l == 0) { d_out[0] = tv; *best = bi; }
}

// ---------------- K5: per-chunk backpointer-function composition (parallel)
__global__ __launch_bounds__(64) void k_chunkF(
    const unsigned char* __restrict__ bptr, unsigned char* __restrict__ F)
{
  const int cidx = blockIdx.x;
  const int g = threadIdx.x;
  if (g >= KTAGS) return;
  const int e = (cidx + 1) * 128 - 1, s = cidx * 128;
  int tag = g;
  for (int t = e; t >= s; --t) tag = bptr[(size_t)t * KTAGS + tag];
  F[cidx * KTAGS + g] = (unsigned char)tag;
}

// ---------------- K6: sequential combine of 64 chunk functions
__global__ void k_bounds(const unsigned char* __restrict__ F,
                         const int* __restrict__ best, int* __restrict__ boundary)
{
  if (threadIdx.x != 0 || blockIdx.x != 0) return;
  int tag = *best;
  boundary[63] = tag;
  for (int cidx = 63; cidx >= 1; --cidx) {
    tag = F[cidx * KTAGS + tag];
    boundary[cidx - 1] = tag;
  }
}

// ---------------- K7: per-chunk path fill (parallel)
__global__ __launch_bounds__(64) void k_path(
    const unsigned char* __restrict__ bptr, const int* __restrict__ boundary,
    float* __restrict__ d_out)
{
  const int cidx = blockIdx.x;
  if (threadIdx.x != 0) return;
  const int e = (cidx + 1) * 128 - 1, s = cidx * 128;
  int tag = boundary[cidx];
  d_out[1 + e] = (float)tag;
  for (int t = e - 1; t >= s; --t) {
    tag = bptr[(size_t)(t + 1) * KTAGS + tag];
    d_out[1 + t] = (float)tag;
  }
}

extern "C" void kernel_launch(void* const* d_in, const int* in_sizes, int n_in,
                              void* d_out, int out_size, void* d_ws, size_t ws_size,
                              hipStream_t stream) {
  (void)in_sizes; (void)n_in; (void)out_size;
  const float* x      = (const float*)d_in[0];
  const float* wih_f  = (const float*)d_in[1];
  const float* whh_f  = (const float*)d_in[2];
  const float* bih_f  = (const float*)d_in[3];
  const float* bhh_f  = (const float*)d_in[4];
  const float* wih_b  = (const float*)d_in[5];
  const float* whh_b  = (const float*)d_in[6];
  const float* bih_b  = (const float*)d_in[7];
  const float* bhh_b  = (const float*)d_in[8];
  const float* h0     = (const float*)d_in[9];
  const float* c0     = (const float*)d_in[10];
  const float* Wtag   = (const float*)d_in[11];
  const float* btag   = (const float*)d_in[12];
  const float* trans  = (const float*)d_in[13];
  float* out = (float*)d_out;
  char* ws = (char*)d_ws;

  // workspace layout
  const bool xg16 = ws_size < ((size_t)168 << 20);   // need ~162MB for fp32 xg path
  size_t off = 0;
  auto alloc = [&](size_t bytes) -> void* {
    void* p = ws + off;
    off += (bytes + 255) & ~(size_t)255;
    return p;
  };
  const size_t xgN = (size_t)2 * T_LEN * G4;
  void* xg            = alloc(xgN * (xg16 ? 2 : 4));
  float* h_hist       = (float*)alloc((size_t)2 * T_LEN * H_DIM * 4);
  float* feats        = (float*)alloc((size_t)T_LEN * KTAGS * 4);
  unsigned char* bptr = (unsigned char*)alloc((size_t)T_LEN * KTAGS);
  unsigned int* flags = (unsigned int*)alloc((size_t)2 * NWG * 32 * 4);
  unsigned char* F    = (unsigned char*)alloc(64 * KTAGS);
  int* boundary       = (int*)alloc(64 * 4);
  int* best           = (int*)alloc(4);

  // flags must start at 0 every call (d_ws is poisoned once and never re-poisoned)
  hipMemsetAsync(flags, 0, (size_t)2 * NWG * 32 * 4, stream);

  const dim3 gx(G4 / 64, T_LEN / 64, 2);
  if (xg16) {
    k_xg<true><<<gx, 256, 0, stream>>>(x, wih_f, bih_f, bhh_f, wih_b, bih_b, bhh_b, xg);
    k_lstm<true><<<64, 512, 0, stream>>>(whh_f, whh_b, h0, c0, xg, h_hist, flags);
  } else {
    k_xg<false><<<gx, 256, 0, stream>>>(x, wih_f, bih_f, bhh_f, wih_b, bih_b, bhh_b, xg);
    k_lstm<false><<<64, 512, 0, stream>>>(whh_f, whh_b, h0, c0, xg, h_hist, flags);
  }
  k_feats<<<T_LEN, 64, 0, stream>>>(h_hist, Wtag, btag, feats);
  k_viterbi<<<1, 64, 0, stream>>>(feats, trans, out, bptr, best);
  k_chunkF<<<64, 64, 0, stream>>>(bptr, F);
  k_bounds<<<1, 64, 0, stream>>>(F, best, boundary);
  k_path<<<64, 64, 0, stream>>>(bptr, boundary, out);
}

// Round 3
// 20974.754 us; speedup vs baseline: 1.4465x; 1.4465x over previous
//
#include <hip/hip_runtime.h>
#include <hip/hip_fp16.h>

#define T_LEN 8192
#define E_DIM 512
#define H_DIM 512
#define G4    2048   // 4*H
#define KTAGS 19
#define START_TAG 17
#define STOP_TAG  18
#define NEGV  (-10000.0f)
#define NWG   16     // workgroups per direction
#define VCH   64     // viterbi chunks
#define VCL   128    // steps per chunk

typedef _Float16 h2v __attribute__((ext_vector_type(2)));
union HU { unsigned int u; h2v h; };

__device__ __forceinline__ float sigmoidf_(float x) { return 1.0f / (1.0f + expf(-x)); }

__device__ __forceinline__ unsigned int pack2(float a, float b) {
  HU u; u.h.x = (_Float16)a; u.h.y = (_Float16)b; return u.u;
}

__device__ __forceinline__ float dot2f(unsigned int a, unsigned int b, float acc) {
#if __has_builtin(__builtin_amdgcn_fdot2)
  HU ua; ua.u = a; HU ub; ub.u = b;
  return __builtin_amdgcn_fdot2(ua.h, ub.h, acc, false);
#else
  HU ua; ua.u = a; HU ub; ub.u = b;
  return acc + (float)ua.h.x * (float)ub.h.x + (float)ua.h.y * (float)ub.h.y;
#endif
}

// ---------------- K1: xg[dir][t][n] = dot(x[t or T-1-t], w_ih[n]) + b_ih[n] + b_hh[n]  (fp16 out)
__global__ __launch_bounds__(256) void k_xg(
    const float* __restrict__ x,
    const float* __restrict__ wih_f, const float* __restrict__ bih_f, const float* __restrict__ bhh_f,
    const float* __restrict__ wih_b, const float* __restrict__ bih_b, const float* __restrict__ bhh_b,
    __half* __restrict__ xg_out)
{
  const int dir = blockIdx.z;
  const float* __restrict__ wih = dir ? wih_b : wih_f;
  const float* __restrict__ bih = dir ? bih_b : bih_f;
  const float* __restrict__ bhh = dir ? bhh_b : bhh_f;
  __shared__ float xs[16][68];
  __shared__ float wsd[16][68];
  const int tid = threadIdx.x;
  const int tm = tid >> 4, tn = tid & 15;
  const int m0 = blockIdx.y * 64, n0 = blockIdx.x * 64;
  const int lr = tid >> 2;
  const int lk = (tid & 3) << 2;
  float acc[4][4] = {{0.f,0.f,0.f,0.f},{0.f,0.f,0.f,0.f},{0.f,0.f,0.f,0.f},{0.f,0.f,0.f,0.f}};
  for (int k0 = 0; k0 < E_DIM; k0 += 16) {
    const int gm = m0 + lr;
    const int xrow = dir ? (T_LEN - 1 - gm) : gm;
    const float4 xa = *reinterpret_cast<const float4*>(&x[(size_t)xrow * E_DIM + k0 + lk]);
    const float4 wa = *reinterpret_cast<const float4*>(&wih[(size_t)(n0 + lr) * E_DIM + k0 + lk]);
    __syncthreads();
    xs[lk+0][lr] = xa.x; xs[lk+1][lr] = xa.y; xs[lk+2][lr] = xa.z; xs[lk+3][lr] = xa.w;
    wsd[lk+0][lr] = wa.x; wsd[lk+1][lr] = wa.y; wsd[lk+2][lr] = wa.z; wsd[lk+3][lr] = wa.w;
    __syncthreads();
    #pragma unroll
    for (int kk = 0; kk < 16; ++kk) {
      const float4 a = *reinterpret_cast<const float4*>(&xs[kk][tm << 2]);
      const float4 b = *reinterpret_cast<const float4*>(&wsd[kk][tn << 2]);
      acc[0][0] += a.x*b.x; acc[0][1] += a.x*b.y; acc[0][2] += a.x*b.z; acc[0][3] += a.x*b.w;
      acc[1][0] += a.y*b.x; acc[1][1] += a.y*b.y; acc[1][2] += a.y*b.z; acc[1][3] += a.y*b.w;
      acc[2][0] += a.z*b.x; acc[2][1] += a.z*b.y; acc[2][2] += a.z*b.z; acc[2][3] += a.z*b.w;
      acc[3][0] += a.w*b.x; acc[3][1] += a.w*b.y; acc[3][2] += a.w*b.z; acc[3][3] += a.w*b.w;
    }
  }
  const int n = n0 + (tn << 2);
  float4 bb;
  bb.x = bih[n+0] + bhh[n+0];
  bb.y = bih[n+1] + bhh[n+1];
  bb.z = bih[n+2] + bhh[n+2];
  bb.w = bih[n+3] + bhh[n+3];
  __half* o = xg_out + (size_t)dir * T_LEN * G4;
  #pragma unroll
  for (int mi = 0; mi < 4; ++mi) {
    const size_t base = (size_t)(m0 + (tm << 2) + mi) * G4 + n;
    unsigned int p0 = pack2(acc[mi][0] + bb.x, acc[mi][1] + bb.y);
    unsigned int p1 = pack2(acc[mi][2] + bb.z, acc[mi][3] + bb.w);
    uint2 st; st.x = p0; st.y = p1;
    *reinterpret_cast<uint2*>(&o[base]) = st;
  }
}

// ---------------- K2: persistent bidirectional LSTM recurrence.
// 32 blocks x 512 thr. dir = (b&7)<4 ? 0:1 (XCD-grouped), idx = (b&3)+4*(b>>3) in 0..15.
// Block owns 32 h (128 gate rows). Wave w: rows w*16..w*16+15; lane chunk c=(l>>4): k in [c*128,c*128+128).
// Weights: 64 half2 VGPRs per thread, pinned with asm so hipcc cannot re-sink the loads.
// h exchange: half2 in 128B-per-producer slots; per-producer release flags.
__global__ __launch_bounds__(512, 2) void k_lstm(
    const float* __restrict__ whh_f, const float* __restrict__ whh_b,
    const float* __restrict__ h0, const float* __restrict__ c0,
    const __half* __restrict__ xg_base, unsigned int* __restrict__ hh16,
    unsigned int* __restrict__ flags)
{
  const int b = blockIdx.x;
  const int dir = ((b & 7) < 4) ? 0 : 1;
  const int idx = (b & 3) + ((b >> 3) << 2);
  const float* __restrict__ whh = dir ? whh_b : whh_f;
  const __half* xg16 = xg_base + (size_t)dir * T_LEN * G4;
  unsigned int* hh = hh16 + (size_t)dir * T_LEN * 512;   // [T][16][32] uints
  unsigned int* fl = flags + dir * NWG * 32;

  const int tid = threadIdx.x;
  const int w = tid >> 6, l = tid & 63;
  const int r = (w << 4) + (l & 15);       // local gate row 0..127
  const int c = l >> 4;                    // k-chunk 0..3
  const int gate = r >> 5, nl = r & 31;
  const int H0 = idx * 32;
  const int R = gate * H_DIM + H0 + nl;    // global gate row

  // --- load + convert weights to 64 half2 VGPRs, pinned ---
  unsigned int wreg[64];
  {
    const float4* wr4 = reinterpret_cast<const float4*>(&whh[(size_t)R * H_DIM + c * 128]);
    #pragma unroll
    for (int mm = 0; mm < 32; ++mm) {
      const float4 v = wr4[mm];
      wreg[2*mm]   = pack2(v.x, v.y);
      wreg[2*mm+1] = pack2(v.z, v.w);
      asm volatile("" : "+v"(wreg[2*mm]), "+v"(wreg[2*mm+1]));
    }
  }

  __shared__ unsigned int h16[256];   // half2 of h(t-1)
  __shared__ float gates[128];
  float cstate = (tid < 32) ? c0[dir * H_DIM + H0 + tid] : 0.f;
  float xcur = (l < 16) ? __half2float(xg16[R]) : 0.f;

  for (int t = 0; t < T_LEN; ++t) {
    float xnext = 0.f;
    if (l < 16 && t + 1 < T_LEN)
      xnext = __half2float(xg16[(size_t)(t + 1) * G4 + R]);

    if (t > 0) {
      if (tid < NWG) {
        const unsigned int* fp = &fl[tid * 32];
        while (__hip_atomic_load(fp, __ATOMIC_ACQUIRE, __HIP_MEMORY_SCOPE_AGENT) < (unsigned)t)
          __builtin_amdgcn_s_sleep(1);
      }
      __syncthreads();
      if (tid < 256) {
        const unsigned int hv = __hip_atomic_load(
            &hh[(size_t)(t - 1) * 512 + (tid >> 4) * 32 + (tid & 15)],
            __ATOMIC_RELAXED, __HIP_MEMORY_SCOPE_AGENT);
        h16[tid] = hv;
      }
    } else {
      if (tid < 256)
        h16[tid] = pack2(h0[dir * H_DIM + 2 * tid], h0[dir * H_DIM + 2 * tid + 1]);
    }
    __syncthreads();

    float acc = 0.f;
    const int base = c * 64;
    #pragma unroll
    for (int m = 0; m < 16; ++m) {
      const int4 hv = *reinterpret_cast<const int4*>(&h16[base + 4 * m]);
      acc = dot2f(wreg[4*m+0], (unsigned int)hv.x, acc);
      acc = dot2f(wreg[4*m+1], (unsigned int)hv.y, acc);
      acc = dot2f(wreg[4*m+2], (unsigned int)hv.z, acc);
      acc = dot2f(wreg[4*m+3], (unsigned int)hv.w, acc);
    }
    acc += __shfl_xor(acc, 16, 64);
    acc += __shfl_xor(acc, 32, 64);
    if (l < 16) gates[r] = acc + xcur;
    __syncthreads();

    if (tid < 32) {
      const float gi = gates[tid];
      const float gf = gates[32 + tid];
      const float gg = gates[64 + tid];
      const float go = gates[96 + tid];
      cstate = sigmoidf_(gf) * cstate + sigmoidf_(gi) * tanhf(gg);
      const float hval = sigmoidf_(go) * tanhf(cstate);
      const float ho = __shfl(hval, tid + 1, 64);  // odd-lane partner (lane31 reads junk, unused)
      if ((tid & 1) == 0)
        __hip_atomic_store(&hh[(size_t)t * 512 + idx * 32 + (tid >> 1)], pack2(hval, ho),
                           __ATOMIC_RELAXED, __HIP_MEMORY_SCOPE_AGENT);
    }
    __syncthreads();   // drains vmcnt: h stores agent-visible before the release flag
    if (tid == 0)
      __hip_atomic_store(&fl[idx * 32], (unsigned)(t + 1),
                         __ATOMIC_RELEASE, __HIP_MEMORY_SCOPE_AGENT);
    xcur = xnext;
  }
}

// ---------------- K3: feats[t][k] = b_tag[k] + [h_f(t), h_b(T-1-t)] . W_tag[k]
__global__ __launch_bounds__(64) void k_feats(
    const unsigned int* __restrict__ hh16, const float* __restrict__ Wtag,
    const float* __restrict__ btag, float* __restrict__ feats)
{
  const int t = blockIdx.x;
  const int tid = threadIdx.x;
  __shared__ float hbuf[1024];   // [hf 512 | hb 512]
  const unsigned int* hfp = hh16 + (size_t)t * 512;
  const unsigned int* hbp = hh16 + (size_t)T_LEN * 512 + (size_t)(T_LEN - 1 - t) * 512;
  for (int m = tid; m < 256; m += 64) {
    HU u; u.u = hfp[(m >> 4) * 32 + (m & 15)];
    hbuf[2*m] = (float)u.h.x; hbuf[2*m+1] = (float)u.h.y;
    HU v; v.u = hbp[(m >> 4) * 32 + (m & 15)];
    hbuf[512 + 2*m] = (float)v.h.x; hbuf[512 + 2*m+1] = (float)v.h.y;
  }
  __syncthreads();
  const int k = tid;
  if (k >= KTAGS) return;
  const float* wr = &Wtag[(size_t)k * 1024];
  float acc = btag[k];
  #pragma unroll 4
  for (int d = 0; d < 256; ++d) {
    const float4 h4 = *reinterpret_cast<const float4*>(&hbuf[4 * d]);
    const float4 w4 = *reinterpret_cast<const float4*>(&wr[4 * d]);
    acc += h4.x*w4.x + h4.y*w4.y + h4.z*w4.z + h4.w*w4.w;
  }
  feats[(size_t)t * KTAGS + k] = acc;
}

// ---------------- K4a: per-chunk (max,+) transfer matrices M_c (19x19), 64 chunks parallel
__global__ __launch_bounds__(384) void k_vit1(
    const float* __restrict__ feats, const float* __restrict__ trans,
    float* __restrict__ Mc)
{
  const int cidx = blockIdx.x;
  const int tid = threadIdx.x;
  const bool act = tid < KTAGS * KTAGS;
  const int i = tid / KTAGS, j = tid % KTAGS;
  __shared__ float M[2][KTAGS * KTAGS];
  __shared__ float ft[KTAGS];
  float trow[KTAGS];
  if (act) {
    #pragma unroll
    for (int kk = 0; kk < KTAGS; ++kk) trow[kk] = trans[i * KTAGS + kk];
  }
  const int s = cidx * VCL;
  if (tid < KTAGS) ft[tid] = feats[(size_t)s * KTAGS + tid];
  __syncthreads();
  if (act) M[0][tid] = trow[j] + ft[i];   // M0[i][j] = T[i][j] + f_s[i]
  for (int u = 1; u < VCL; ++u) {
    __syncthreads();
    if (tid < KTAGS) ft[tid] = feats[(size_t)(s + u) * KTAGS + tid];
    __syncthreads();
    const float* Mr = M[(u + 1) & 1];
    if (act) {
      float m = -3.4e38f;
      #pragma unroll
      for (int kk = 0; kk < KTAGS; ++kk)
        m = fmaxf(m, trow[kk] + Mr[kk * KTAGS + j]);
      M[u & 1][tid] = m + ft[i];
    }
  }
  __syncthreads();
  if (act) Mc[(size_t)cidx * (KTAGS * KTAGS) + tid] = M[(VCL - 1) & 1][tid];
}

// ---------------- K4b: sequential prefix over 64 chunk matrices; chunk-start fvs + terminal
__global__ __launch_bounds__(64) void k_vit2(
    const float* __restrict__ Mc, const float* __restrict__ trans,
    float* __restrict__ fvs, float* __restrict__ d_out, int* __restrict__ best)
{
  const int l = threadIdx.x;
  const bool act = l < KTAGS;
  float fv = act ? ((l == START_TAG) ? 0.f : NEGV) : -3.4e38f;
  for (int cidx = 0; cidx < VCH; ++cidx) {
    if (act) fvs[cidx * KTAGS + l] = fv;
    const float* Mr = &Mc[(size_t)cidx * (KTAGS * KTAGS) + (act ? l : 0) * KTAGS];
    float m = -3.4e38f;
    #pragma unroll
    for (int jj = 0; jj < KTAGS; ++jj) {
      const float fvj = __shfl(fv, jj, 64);
      m = fmaxf(m, Mr[jj] + fvj);
    }
    fv = act ? m : -3.4e38f;
  }
  const float trs = act ? trans[STOP_TAG * KTAGS + l] : 0.f;
  float tv = act ? (fv + trs) : -3.4e38f;
  int bi = l;
  #pragma unroll
  for (int off = 1; off < 64; off <<= 1) {
    const float ov = __shfl_xor(tv, off, 64);
    const int oi = __shfl_xor(bi, off, 64);
    if (ov > tv || (ov == tv && oi < bi)) { tv = ov; bi = oi; }
  }
  if (l == 0) { d_out[0] = tv; *best = bi; }
}

// ---------------- K4c: per-chunk backpointer generation (64 chunks parallel)
__global__ __launch_bounds__(64) void k_vit3(
    const float* __restrict__ feats, const float* __restrict__ trans,
    const float* __restrict__ fvs, unsigned char* __restrict__ bptr)
{
  const int cidx = blockIdx.x;
  const int l = threadIdx.x;
  const bool act = l < KTAGS;
  float trow[KTAGS];
  #pragma unroll
  for (int jj = 0; jj < KTAGS; ++jj)
    trow[jj] = act ? trans[l * KTAGS + jj] : NEGV;
  float fv = act ? fvs[cidx * KTAGS + l] : -3.4e38f;
  const int s = cidx * VCL;
  for (int u = 0; u < VCL; ++u) {
    const int tt = s + u;
    const float fcur = act ? feats[(size_t)tt * KTAGS + l] : 0.f;
    float v[KTAGS];
    #pragma unroll
    for (int jj = 0; jj < KTAGS; ++jj)
      v[jj] = __shfl(fv, jj, 64) + trow[jj];
    float a[10];
    #pragma unroll
    for (int q = 0; q < 9; ++q) a[q] = fmaxf(v[2*q], v[2*q+1]);
    a[9] = v[18];
    const float mv = fmaxf(fmaxf(fmaxf(fmaxf(a[0],a[1]), fmaxf(a[2],a[3])),
                                 fmaxf(fmaxf(a[4],a[5]), fmaxf(a[6],a[7]))), fmaxf(a[8],a[9]));
    unsigned bits = 0u;
    #pragma unroll
    for (int jj = 0; jj < KTAGS; ++jj)
      bits |= (v[jj] == mv) ? (1u << jj) : 0u;
    const int am = __ffs(bits) - 1;
    fv = mv + fcur;
    if (act) bptr[(size_t)tt * KTAGS + l] = (unsigned char)am;
  }
}

// ---------------- K5: per-chunk backpointer-function composition (parallel)
__global__ __launch_bounds__(64) void k_chunkF(
    const unsigned char* __restrict__ bptr, unsigned char* __restrict__ F)
{
  const int cidx = blockIdx.x;
  const int g = threadIdx.x;
  if (g >= KTAGS) return;
  const int e = (cidx + 1) * 128 - 1, s = cidx * 128;
  int tag = g;
  for (int t = e; t >= s; --t) tag = bptr[(size_t)t * KTAGS + tag];
  F[cidx * KTAGS + g] = (unsigned char)tag;
}

// ---------------- K6: sequential combine of 64 chunk functions
__global__ void k_bounds(const unsigned char* __restrict__ F,
                         const int* __restrict__ best, int* __restrict__ boundary)
{
  if (threadIdx.x != 0 || blockIdx.x != 0) return;
  int tag = *best;
  boundary[63] = tag;
  for (int cidx = 63; cidx >= 1; --cidx) {
    tag = F[cidx * KTAGS + tag];
    boundary[cidx - 1] = tag;
  }
}

// ---------------- K7: per-chunk path fill (parallel)
__global__ __launch_bounds__(64) void k_path(
    const unsigned char* __restrict__ bptr, const int* __restrict__ boundary,
    float* __restrict__ d_out)
{
  const int cidx = blockIdx.x;
  if (threadIdx.x != 0) return;
  const int e = (cidx + 1) * 128 - 1, s = cidx * 128;
  int tag = boundary[cidx];
  d_out[1 + e] = (float)tag;
  for (int t = e - 1; t >= s; --t) {
    tag = bptr[(size_t)(t + 1) * KTAGS + tag];
    d_out[1 + t] = (float)tag;
  }
}

extern "C" void kernel_launch(void* const* d_in, const int* in_sizes, int n_in,
                              void* d_out, int out_size, void* d_ws, size_t ws_size,
                              hipStream_t stream) {
  (void)in_sizes; (void)n_in; (void)out_size; (void)ws_size;
  const float* x      = (const float*)d_in[0];
  const float* wih_f  = (const float*)d_in[1];
  const float* whh_f  = (const float*)d_in[2];
  const float* bih_f  = (const float*)d_in[3];
  const float* bhh_f  = (const float*)d_in[4];
  const float* wih_b  = (const float*)d_in[5];
  const float* whh_b  = (const float*)d_in[6];
  const float* bih_b  = (const float*)d_in[7];
  const float* bhh_b  = (const float*)d_in[8];
  const float* h0     = (const float*)d_in[9];
  const float* c0     = (const float*)d_in[10];
  const float* Wtag   = (const float*)d_in[11];
  const float* btag   = (const float*)d_in[12];
  const float* trans  = (const float*)d_in[13];
  float* out = (float*)d_out;
  char* ws = (char*)d_ws;

  size_t off = 0;
  auto alloc = [&](size_t bytes) -> void* {
    void* p = ws + off;
    off += (bytes + 255) & ~(size_t)255;
    return p;
  };
  __half* xg          = (__half*)alloc((size_t)2 * T_LEN * G4 * 2);          // 67.1MB
  unsigned int* hh16  = (unsigned int*)alloc((size_t)2 * T_LEN * 512 * 4);   // 33.55MB
  float* feats        = (float*)alloc((size_t)T_LEN * KTAGS * 4);
  unsigned char* bptr = (unsigned char*)alloc((size_t)T_LEN * KTAGS);
  unsigned int* flags = (unsigned int*)alloc((size_t)2 * NWG * 32 * 4);
  float* Mc           = (float*)alloc((size_t)VCH * KTAGS * KTAGS * 4);
  float* fvs          = (float*)alloc((size_t)VCH * KTAGS * 4);
  unsigned char* F    = (unsigned char*)alloc(VCH * KTAGS);
  int* boundary       = (int*)alloc(VCH * 4);
  int* best           = (int*)alloc(4);

  hipMemsetAsync(flags, 0, (size_t)2 * NWG * 32 * 4, stream);

  const dim3 gx(G4 / 64, T_LEN / 64, 2);
  k_xg<<<gx, 256, 0, stream>>>(x, wih_f, bih_f, bhh_f, wih_b, bih_b, bhh_b, xg);
  k_lstm<<<32, 512, 0, stream>>>(whh_f, whh_b, h0, c0, xg, hh16, flags);
  k_feats<<<T_LEN, 64, 0, stream>>>(hh16, Wtag, btag, feats);
  k_vit1<<<VCH, 384, 0, stream>>>(feats, trans, Mc);
  k_vit2<<<1, 64, 0, stream>>>(Mc, trans, fvs, out, best);
  k_vit3<<<VCH, 64, 0, stream>>>(feats, trans, fvs, bptr);
  k_chunkF<<<VCH, 64, 0, stream>>>(bptr, F);
  k_bounds<<<1, 64, 0, stream>>>(F, best, boundary);
  k_path<<<VCH, 64, 0, stream>>>(bptr, boundary, out);
}